// Round 10
// baseline (12538.488 us; speedup 1.0000x reference)
//
#include <hip/hip_runtime.h>

#define T_STEPS 4096
#define HID     512
#define NCH     256
#define DIM     128
#define VOCAB   32000
#define GRU_WGS 16

// ---------- fast transcendentals (hardware v_exp_f32 path; R3-proven) ----------
__device__ __forceinline__ float fast_sigmoid(float x) {
  x = fminf(fmaxf(x, -30.f), 30.f);
  const float e = __expf(-x);
  return __fdividef(1.f, 1.f + e);
}
__device__ __forceinline__ float fast_tanh(float x) {
  x = fminf(fmaxf(x, -15.f), 15.f);
  const float e = __expf(2.f * x);
  return __fdividef(e - 1.f, e + 1.f);
}

// ---------- DPP 16-lane (row) sum; row-lane 0 holds the total (R3-proven) ----------
template <int CTRL>
__device__ __forceinline__ float dpp_add(float v) {
  const int s = __builtin_amdgcn_update_dpp(0, __float_as_int(v), CTRL, 0xF, 0xF, true);
  return v + __int_as_float(s);
}
__device__ __forceinline__ float red16(float v) {
  v = dpp_add<0xB1>(v);   // quad_perm xor1
  v = dpp_add<0x4E>(v);   // quad_perm xor2
  v = dpp_add<0x124>(v);  // row_ror:4
  v = dpp_add<0x128>(v);  // row_ror:8
  return v;               // row-lane 0 (p==0) holds the 16-lane total
}

// ============================ GRU ============================
// 16 WGs x 512 threads; 16-lane teams per output j (32 outputs/WG).
// PRIVATE per-WG mailboxes: 16 replicas of the 2x512 tagged u64 buffer.
// Leaders publish h[j] to ALL 16 replicas (fire-and-forget agent stores);
// each WG polls only ITS replica -> no cross-WG line contention at the MALL.
// Per poll round: deposit polled value to LDS unconditionally, issue next
// round's load, then gate with ONE __syncthreads_and (gate = deposit barrier).
__global__ __launch_bounds__(512) void gru_kernel(
    const float* __restrict__ x,
    const float* __restrict__ w_ih,
    const float* __restrict__ w_hh,
    const float* __restrict__ b_ih,
    const float* __restrict__ b_hh,
    unsigned long long* hg,            // 16 replicas x 2*512 tagged slots (zeroed)
    float* __restrict__ evolved)       // (4096, 512)
{
  __shared__ float hs[HID];            // 2 KB
  __shared__ float xl[T_STEPS];        // 16 KB: x staged once
  const int tid  = threadIdx.x;
  const int wave = tid >> 6;           // 0..7
  const int lane = tid & 63;
  const int team = lane >> 4;          // 0..3
  const int p    = lane & 15;          // k-slice index within team
  const int pr   = p & 7;              // bank-rotation amount
  const int j    = blockIdx.x * 32 + wave * 4 + team;   // 0..511
  const int k0   = p * 32;
  unsigned long long* mybox = hg + (size_t)blockIdx.x * 1024;  // this WG's replica

  // stage x into LDS (coalesced float4), consumed after first barrier
  {
    const float4* x4 = reinterpret_cast<const float4*>(x);
    float4* xl4 = reinterpret_cast<float4*>(xl);
    for (int u = tid; u < T_STEPS / 4; u += 512) xl4[u] = x4[u];
  }

  // weights rows j (r), 512+j (z), 1024+j (n), cols [32p,32p+32), rotated order
  float4 w[3][8];
#pragma unroll
  for (int d = 0; d < 3; ++d) {
    const float4* wr = reinterpret_cast<const float4*>(w_hh + (size_t)(d * HID + j) * HID);
#pragma unroll
    for (int qq = 0; qq < 8; ++qq) {
      const int r = (qq + pr) & 7;
      w[d][qq] = wr[p * 8 + r];
    }
  }
  float c3[3], bi3[3], bh3[3];
#pragma unroll
  for (int d = 0; d < 3; ++d) {
    int r = d * HID + j;
    c3[d]  = w_ih[r*4+0] + 0.1f*w_ih[r*4+1] + 0.01f*w_ih[r*4+2] + 0.001f*w_ih[r*4+3];
    bi3[d] = b_ih[r];
    bh3[d] = b_hh[r];
  }
  __syncthreads();   // xl[] visible to all before first use

  float hprev = 0.0f;  // leader lanes (p==0) carry h[j]
  for (int s = 1; s <= T_STEPS; ++s) {
    const int rb = (s - 1) & 1;
    const int wb = s & 1;
    const unsigned int want = (unsigned int)(s - 1);
    const unsigned long long* rs = mybox + rb * HID;

    const float xt = xl[s - 1];

    // ---- poll own replica: 1 slot/thread; deposit-every-round; merged barrier ----
    unsigned long long v =
        __hip_atomic_load(rs + tid, __ATOMIC_RELAXED, __HIP_MEMORY_SCOPE_AGENT);
    for (;;) {
      hs[tid] = __uint_as_float((unsigned int)v);          // deposit (checked value)
      const unsigned long long nv =                         // prefetch next round
          __hip_atomic_load(rs + tid, __ATOMIC_RELAXED, __HIP_MEMORY_SCOPE_AGENT);
      if (__syncthreads_and((unsigned int)(v >> 32) == want)) break;
      v = nv;
    }

    // ---- dot products from LDS (rotated order; sum is order-invariant) ----
    float a0 = 0.f, a1 = 0.f, a2 = 0.f;
#pragma unroll
    for (int qq = 0; qq < 8; ++qq) {
      const int r = (qq + pr) & 7;
      const float4 h4 = *reinterpret_cast<const float4*>(&hs[k0 + 4 * r]);
      a0 = fmaf(w[0][qq].x, h4.x, a0);
      a0 = fmaf(w[0][qq].y, h4.y, a0);
      a0 = fmaf(w[0][qq].z, h4.z, a0);
      a0 = fmaf(w[0][qq].w, h4.w, a0);
      a1 = fmaf(w[1][qq].x, h4.x, a1);
      a1 = fmaf(w[1][qq].y, h4.y, a1);
      a1 = fmaf(w[1][qq].z, h4.z, a1);
      a1 = fmaf(w[1][qq].w, h4.w, a1);
      a2 = fmaf(w[2][qq].x, h4.x, a2);
      a2 = fmaf(w[2][qq].y, h4.y, a2);
      a2 = fmaf(w[2][qq].z, h4.z, a2);
      a2 = fmaf(w[2][qq].w, h4.w, a2);
    }

    // ---- DPP team reduce (VALU-only; leaders are row-lane 0) ----
    a0 = red16(a0); a1 = red16(a1); a2 = red16(a2);

    if (p == 0) {
      const float rg = fast_sigmoid(fmaf(xt, c3[0], bi3[0]) + a0 + bh3[0]);
      const float zg = fast_sigmoid(fmaf(xt, c3[1], bi3[1]) + a1 + bh3[1]);
      const float ng = fast_tanh(fmaf(xt, c3[2], bi3[2]) + rg * (a2 + bh3[2]));
      const float hn = (1.0f - zg) * ng + zg * hprev;
      hprev = hn;
      const unsigned long long pk =
          ((unsigned long long)(unsigned int)s << 32) | (unsigned long long)__float_as_uint(hn);
      // publish to all 16 replicas (fire-and-forget; off critical path)
      unsigned long long* dst = hg + (size_t)wb * HID + j;
#pragma unroll
      for (int wgt = 0; wgt < GRU_WGS; ++wgt)
        __hip_atomic_store(dst + wgt * 1024, pk, __ATOMIC_RELAXED, __HIP_MEMORY_SCOPE_AGENT);
      evolved[(size_t)(s - 1) * HID + j] = hn;
    }
  }
}

// ==================== FFT -> phase filter -> IFFT (radix-4) ====================
__device__ __forceinline__ float2 cmul(float2 a, float2 b) {
  return make_float2(a.x * b.x - a.y * b.y, a.x * b.y + a.y * b.x);
}

// 4096-pt radix-4 DIT; input digit-reversed (base-4), output natural order.
__device__ __forceinline__ void fft4096_r4(float2* buf, const float2* tw, int tid)
{
  for (int st = 0; st < 6; ++st) {
    const int q  = 1 << (2 * st);        // quarter
    const int ts = 10 - 2 * st;          // twiddle step shift: 4096/len = 1<<ts
    for (int i = tid; i < 1024; i += 256) {
      const int blk  = i >> (2 * st);
      const int pos  = i & (q - 1);
      const int base = blk * (q << 2) + pos;
      const float2 u0 = buf[base];
      float2 u1 = buf[base + q];
      float2 u2 = buf[base + 2 * q];
      float2 u3 = buf[base + 3 * q];
      const int k = pos << ts;           // 3k < 3072 < 4096
      u1 = cmul(u1, tw[k]);
      u2 = cmul(u2, tw[2 * k]);
      u3 = cmul(u3, tw[3 * k]);
      const float ax = u0.x + u2.x, ay = u0.y + u2.y;
      const float bx = u0.x - u2.x, by = u0.y - u2.y;
      const float cx = u1.x + u3.x, cy = u1.y + u3.y;
      const float dx = u1.x - u3.x, dy = u1.y - u3.y;
      buf[base]         = make_float2(ax + cx, ay + cy);
      buf[base + q]     = make_float2(bx + dy, by - dx);   // b - i*d
      buf[base + 2 * q] = make_float2(ax - cx, ay - cy);
      buf[base + 3 * q] = make_float2(bx - dy, by + dx);   // b + i*d
    }
    __syncthreads();
  }
}

__device__ __forceinline__ int digitrev4(int t) {   // reverse 6 base-4 digits
  int r = 0;
#pragma unroll
  for (int d = 0; d < 6; ++d) { r = (r << 2) | (t & 3); t >>= 2; }
  return r;
}

__global__ __launch_bounds__(256) void fft_kernel(
    const float* __restrict__ evolved,   // (4096, 512)
    const float* __restrict__ alpha_p,
    float* __restrict__ ft)              // (4096, 256)
{
  __shared__ float2 buf[4096];           // 32 KB
  __shared__ float2 tw[4096];            // 32 KB twiddles
  const int tid = threadIdx.x;
  const int c = blockIdx.x;
  const float alpha = alpha_p[0];

  // twiddle table: tw[k] = exp(-i*2*pi*k/4096), libm accuracy, one-time
  for (int k = tid; k < 4096; k += 256) {
    float sn, cs;
    sincosf(-6.283185307179586f * (float)k / 4096.0f, &sn, &cs);
    tw[k] = make_float2(cs, sn);
  }

  // load channel with base-4 digit reversal; real = ch 2c, imag = ch 2c+1
  for (int t = tid; t < 4096; t += 256) {
    buf[digitrev4(t)] = make_float2(evolved[(size_t)t * HID + 2 * c],
                                    evolved[(size_t)t * HID + 2 * c + 1]);
  }
  __syncthreads();
  fft4096_r4(buf, tw, tid);

  // phase filter, then conjugate (inverse via conj-fft)
  for (int t = tid; t < 4096; t += 256) {
    float2 v = buf[t];
    const float km = sqrtf(v.x * v.x + v.y * v.y) + 1e-10f;
    const float pf = alpha * atanf(logf(km));
    float sn, cs;
    sincosf(pf, &sn, &cs);
    const float rr = v.x * cs - v.y * sn;
    const float ii = v.x * sn + v.y * cs;
    buf[t] = make_float2(rr, -ii);
  }
  __syncthreads();
  // digit-reverse permute in place (involution -> disjoint pair swaps)
  for (int t = tid; t < 4096; t += 256) {
    const int r = digitrev4(t);
    if (r > t) { float2 tmp = buf[t]; buf[t] = buf[r]; buf[r] = tmp; }
  }
  __syncthreads();
  fft4096_r4(buf, tw, tid);

  const float inv = 1.0f / 4096.0f;
  for (int t = tid; t < 4096; t += 256) {
    ft[(size_t)t * NCH + c] = buf[t].x * inv;   // Re(ifft) = Re(fft(conj))/N
  }
}

// ==================== coh = ft @ pc_w.T + pc_b ====================
__global__ __launch_bounds__(256) void coh_kernel(
    const float* __restrict__ ft,     // (4096, 256)
    const float* __restrict__ pcw,    // (128, 256)
    const float* __restrict__ pcb,    // (128)
    float* __restrict__ x0)           // (4096, 128)
{
  __shared__ float wT[64][132];
  __shared__ float fT[64][68];
  const int tid = threadIdx.x;
  const int rg = tid >> 4;
  const int cg = tid & 15;
  const int t0 = blockIdx.x * 64;
  float acc[4][8];
#pragma unroll
  for (int i = 0; i < 4; ++i)
#pragma unroll
    for (int jj = 0; jj < 8; ++jj) acc[i][jj] = 0.f;

  for (int kt = 0; kt < 256; kt += 64) {
    __syncthreads();
    for (int u = tid; u < 64 * DIM; u += 256) {
      const int col = u >> 6, kk = u & 63;
      wT[kk][col] = pcw[col * 256 + kt + kk];
    }
    for (int u = tid; u < 64 * 64; u += 256) {
      const int row = u >> 6, kk = u & 63;
      fT[kk][row] = ft[(size_t)(t0 + row) * NCH + kt + kk];
    }
    __syncthreads();
#pragma unroll 4
    for (int k = 0; k < 64; ++k) {
      const float4 a  = *(const float4*)&fT[k][rg * 4];
      const float4 w0 = *(const float4*)&wT[k][cg * 8];
      const float4 w1 = *(const float4*)&wT[k][cg * 8 + 4];
      const float av[4] = {a.x, a.y, a.z, a.w};
      const float wv[8] = {w0.x, w0.y, w0.z, w0.w, w1.x, w1.y, w1.z, w1.w};
#pragma unroll
      for (int i = 0; i < 4; ++i)
#pragma unroll
        for (int jj = 0; jj < 8; ++jj)
          acc[i][jj] = fmaf(av[i], wv[jj], acc[i][jj]);
    }
  }
#pragma unroll
  for (int i = 0; i < 4; ++i) {
    const int t = t0 + rg * 4 + i;
#pragma unroll
    for (int jj = 0; jj < 8; ++jj)
      x0[(size_t)t * DIM + cg * 8 + jj] = acc[i][jj] + pcb[cg * 8 + jj];
  }
}

// ==================== logits = (x0@Pre.T)^2 + (x0@Pim.T)^2 ====================
__global__ __launch_bounds__(256) void logits_kernel(
    const float* __restrict__ x0,      // (4096, 128)
    const float* __restrict__ patre,   // (32000, 128)
    const float* __restrict__ patim,   // (32000, 128)
    float* __restrict__ out)           // (4096, 32000)
{
  __shared__ float aT[32][68];
  __shared__ float brT[32][132];
  __shared__ float biT[32][132];
  const int tid = threadIdx.x;
  const int tx = tid & 31;
  const int ty = tid >> 5;
  const int m0 = blockIdx.y * 64;
  const int n0 = blockIdx.x * 128;
  float accr[8][4], acci[8][4];
#pragma unroll
  for (int i = 0; i < 8; ++i)
#pragma unroll
    for (int jj = 0; jj < 4; ++jj) { accr[i][jj] = 0.f; acci[i][jj] = 0.f; }

  for (int kt = 0; kt < 128; kt += 32) {
    __syncthreads();
    for (int u = tid; u < 64 * 32; u += 256) {
      const int mm = u >> 5, kk = u & 31;
      aT[kk][mm] = x0[(size_t)(m0 + mm) * DIM + kt + kk];
    }
    for (int u = tid; u < 128 * 32; u += 256) {
      const int nn = u >> 5, kk = u & 31;
      brT[kk][nn] = patre[(size_t)(n0 + nn) * DIM + kt + kk];
      biT[kk][nn] = patim[(size_t)(n0 + nn) * DIM + kt + kk];
    }
    __syncthreads();
#pragma unroll 4
    for (int k = 0; k < 32; ++k) {
      const float4 q0 = *(const float4*)&aT[k][ty * 8];
      const float4 q1 = *(const float4*)&aT[k][ty * 8 + 4];
      const float4 br = *(const float4*)&brT[k][tx * 4];
      const float4 bi = *(const float4*)&biT[k][tx * 4];
      const float av[8]  = {q0.x, q0.y, q0.z, q0.w, q1.x, q1.y, q1.z, q1.w};
      const float brv[4] = {br.x, br.y, br.z, br.w};
      const float biv[4] = {bi.x, bi.y, bi.z, bi.w};
#pragma unroll
      for (int i = 0; i < 8; ++i)
#pragma unroll
        for (int jj = 0; jj < 4; ++jj) {
          accr[i][jj] = fmaf(av[i], brv[jj], accr[i][jj]);
          acci[i][jj] = fmaf(av[i], biv[jj], acci[i][jj]);
        }
    }
  }
#pragma unroll
  for (int i = 0; i < 8; ++i) {
    const size_t m = (size_t)(m0 + ty * 8 + i);
    float4 o;
    o.x = accr[i][0] * accr[i][0] + acci[i][0] * acci[i][0];
    o.y = accr[i][1] * accr[i][1] + acci[i][1] * acci[i][1];
    o.z = accr[i][2] * accr[i][2] + acci[i][2] * acci[i][2];
    o.w = accr[i][3] * accr[i][3] + acci[i][3] * acci[i][3];
    *(float4*)&out[m * VOCAB + n0 + tx * 4] = o;
  }
}

// ============================ launch ============================
extern "C" void kernel_launch(void* const* d_in, const int* in_sizes, int n_in,
                              void* d_out, int out_size, void* d_ws, size_t ws_size,
                              hipStream_t stream)
{
  const float* x     = (const float*)d_in[0];
  const float* w_ih  = (const float*)d_in[1];
  const float* w_hh  = (const float*)d_in[2];
  const float* b_ih  = (const float*)d_in[3];
  const float* b_hh  = (const float*)d_in[4];
  const float* alpha = (const float*)d_in[5];
  const float* pc_w  = (const float*)d_in[6];
  const float* pc_b  = (const float*)d_in[7];
  const float* patre = (const float*)d_in[8];
  const float* patim = (const float*)d_in[9];

  float* out = (float*)d_out;
  // Intermediates parked inside d_out (logits_kernel overwrites all of d_out last)
  float* evolved = out;                 // 4096*512 floats
  float* ft      = out + 4194304;       // 4096*256 floats

  unsigned long long* hg = (unsigned long long*)d_ws;   // 16 replicas * 8 KB = 128 KB
  float* x0 = (float*)((char*)d_ws + 131072);           // 4096*128 = 2 MB

  // Reset all mailbox replicas every launch (tag 0 == h0 == 0); replay-safe.
  hipMemsetAsync(d_ws, 0, 131072, stream);

  gru_kernel<<<GRU_WGS, 512, 0, stream>>>(x, w_ih, w_hh, b_ih, b_hh, hg, evolved);
  fft_kernel<<<256, 256, 0, stream>>>(evolved, alpha, ft);
  coh_kernel<<<64, 256, 0, stream>>>(ft, pc_w, pc_b, x0);
  logits_kernel<<<dim3(250, 64), 256, 0, stream>>>(x0, patre, patim, out);
}

// Round 11
// 10167.616 us; speedup vs baseline: 1.2332x; 1.2332x over previous
//
#include <hip/hip_runtime.h>

#define T_STEPS 4096
#define HID     512
#define NCH     256
#define DIM     128
#define VOCAB   32000
#define GRU_WGS 32

// ---------- fast transcendentals (hardware v_exp_f32 path; R3-proven) ----------
__device__ __forceinline__ float fast_sigmoid(float x) {
  x = fminf(fmaxf(x, -30.f), 30.f);
  const float e = __expf(-x);
  return __fdividef(1.f, 1.f + e);
}
__device__ __forceinline__ float fast_tanh(float x) {
  x = fminf(fmaxf(x, -15.f), 15.f);
  const float e = __expf(2.f * x);
  return __fdividef(e - 1.f, e + 1.f);
}

// ---------- DPP 16-lane (row) sum; row-lane 0 holds the total (R3-proven) ----------
template <int CTRL>
__device__ __forceinline__ float dpp_add(float v) {
  const int s = __builtin_amdgcn_update_dpp(0, __float_as_int(v), CTRL, 0xF, 0xF, true);
  return v + __int_as_float(s);
}
__device__ __forceinline__ float red16(float v) {
  v = dpp_add<0xB1>(v);   // quad_perm xor1
  v = dpp_add<0x4E>(v);   // quad_perm xor2
  v = dpp_add<0x124>(v);  // row_ror:4
  v = dpp_add<0x128>(v);  // row_ror:8
  return v;               // row-lane 0 (p==0) holds the 16-lane total
}

// ============================ GRU ============================
// R8-proven structure (best measured: 9.19 ms). 32 WGs x 256 threads,
// 16-lane teams per output j. Tagged u64 slots (hi32=step tag, lo32=h bits)
// in d_ws, agent scope. Poll: 2 slots/thread with next-round prefetch issued
// before the barrier. ONE delta vs R8: leaders publish via fire-and-forget
// atomic_exchange (RMW executes at the MALL coherence point -> value visible
// at op retire, skipping CU-side store-buffer drain).
__global__ __launch_bounds__(256) void gru_kernel(
    const float* __restrict__ x,
    const float* __restrict__ w_ih,
    const float* __restrict__ w_hh,
    const float* __restrict__ b_ih,
    const float* __restrict__ b_hh,
    unsigned long long* hg,            // 2 * 512 tagged slots (zeroed each launch)
    float* __restrict__ evolved)       // (4096, 512)
{
  __shared__ float hs[HID];            // 2 KB
  __shared__ float xl[T_STEPS];        // 16 KB: x staged once
  const int tid  = threadIdx.x;
  const int wave = tid >> 6;
  const int lane = tid & 63;
  const int team = lane >> 4;          // 0..3
  const int p    = lane & 15;          // k-slice index within team
  const int pr   = p & 7;              // bank-rotation amount
  const int j    = blockIdx.x * 16 + wave * 4 + team;   // 0..511
  const int k0   = p * 32;

  // stage x into LDS (coalesced float4), consumed after first barrier
  {
    const float4* x4 = reinterpret_cast<const float4*>(x);
    float4* xl4 = reinterpret_cast<float4*>(xl);
    for (int u = tid; u < T_STEPS / 4; u += 256) xl4[u] = x4[u];
  }

  // weights rows j (r), 512+j (z), 1024+j (n), cols [32p,32p+32), rotated order
  float4 w[3][8];
#pragma unroll
  for (int d = 0; d < 3; ++d) {
    const float4* wr = reinterpret_cast<const float4*>(w_hh + (size_t)(d * HID + j) * HID);
#pragma unroll
    for (int qq = 0; qq < 8; ++qq) {
      const int r = (qq + pr) & 7;
      w[d][qq] = wr[p * 8 + r];
    }
  }
  float c3[3], bi3[3], bh3[3];
#pragma unroll
  for (int d = 0; d < 3; ++d) {
    int r = d * HID + j;
    c3[d]  = w_ih[r*4+0] + 0.1f*w_ih[r*4+1] + 0.01f*w_ih[r*4+2] + 0.001f*w_ih[r*4+3];
    bi3[d] = b_ih[r];
    bh3[d] = b_hh[r];
  }
  __syncthreads();   // xl[] visible to all before first use

  float hprev = 0.0f;  // leader lanes (p==0) carry h[j]
  for (int s = 1; s <= T_STEPS; ++s) {
    const int rb = (s - 1) & 1;
    const int wb = s & 1;
    const unsigned int want = (unsigned int)(s - 1);
    const unsigned long long* rs = hg + rb * HID;

    const float xt = xl[s - 1];

    // ---- WG-cooperative poll with next-round prefetch (R8-proven) ----
    unsigned long long vA, vB;
    vA = __hip_atomic_load(rs + 2 * tid,     __ATOMIC_RELAXED, __HIP_MEMORY_SCOPE_AGENT);
    vB = __hip_atomic_load(rs + 2 * tid + 1, __ATOMIC_RELAXED, __HIP_MEMORY_SCOPE_AGENT);
    for (;;) {
      const bool ok = ((unsigned int)(vA >> 32) == want) &
                      ((unsigned int)(vB >> 32) == want);
      // issue next round's loads BEFORE the barrier: latency hides under it
      const unsigned long long nA =
          __hip_atomic_load(rs + 2 * tid,     __ATOMIC_RELAXED, __HIP_MEMORY_SCOPE_AGENT);
      const unsigned long long nB =
          __hip_atomic_load(rs + 2 * tid + 1, __ATOMIC_RELAXED, __HIP_MEMORY_SCOPE_AGENT);
      if (__syncthreads_and(ok)) break;
      vA = nA; vB = nB;
    }
    hs[2 * tid]     = __uint_as_float((unsigned int)vA);
    hs[2 * tid + 1] = __uint_as_float((unsigned int)vB);
    __syncthreads();

    // ---- dot products from LDS (rotated order; sum is order-invariant) ----
    float a0 = 0.f, a1 = 0.f, a2 = 0.f;
#pragma unroll
    for (int qq = 0; qq < 8; ++qq) {
      const int r = (qq + pr) & 7;
      const float4 h4 = *reinterpret_cast<const float4*>(&hs[k0 + 4 * r]);
      a0 = fmaf(w[0][qq].x, h4.x, a0);
      a0 = fmaf(w[0][qq].y, h4.y, a0);
      a0 = fmaf(w[0][qq].z, h4.z, a0);
      a0 = fmaf(w[0][qq].w, h4.w, a0);
      a1 = fmaf(w[1][qq].x, h4.x, a1);
      a1 = fmaf(w[1][qq].y, h4.y, a1);
      a1 = fmaf(w[1][qq].z, h4.z, a1);
      a1 = fmaf(w[1][qq].w, h4.w, a1);
      a2 = fmaf(w[2][qq].x, h4.x, a2);
      a2 = fmaf(w[2][qq].y, h4.y, a2);
      a2 = fmaf(w[2][qq].z, h4.z, a2);
      a2 = fmaf(w[2][qq].w, h4.w, a2);
    }

    // ---- DPP team reduce (VALU-only; leaders are row-lane 0) ----
    a0 = red16(a0); a1 = red16(a1); a2 = red16(a2);

    if (p == 0) {
      const float rg = fast_sigmoid(fmaf(xt, c3[0], bi3[0]) + a0 + bh3[0]);
      const float zg = fast_sigmoid(fmaf(xt, c3[1], bi3[1]) + a1 + bh3[1]);
      const float ng = fast_tanh(fmaf(xt, c3[2], bi3[2]) + rg * (a2 + bh3[2]));
      const float hn = (1.0f - zg) * ng + zg * hprev;
      hprev = hn;
      const unsigned long long pk =
          ((unsigned long long)(unsigned int)s << 32) | (unsigned long long)__float_as_uint(hn);
      // fire-and-forget RMW publish: executes at the MALL coherence point
      (void)__hip_atomic_exchange(hg + wb * HID + j, pk,
                                  __ATOMIC_RELAXED, __HIP_MEMORY_SCOPE_AGENT);
      evolved[(size_t)(s - 1) * HID + j] = hn;
    }
  }
}

// ==================== FFT -> phase filter -> IFFT ====================
// 4096-pt radix-2 DIT with a 2048-entry LDS twiddle table (R8-proven).
__device__ __forceinline__ void fft4096(float2* buf, const float2* tw, int tid)
{
  for (int st = 0; st < 12; ++st) {
    const int half = 1 << st;
    const int sh = 11 - st;
    for (int i = tid; i < 2048; i += 256) {
      const int blk = i >> st;
      const int pos = i & (half - 1);
      const int idx = blk * (2 << st) + pos;
      const float2 t = tw[pos << sh];       // (cos, sin) of -2*pi*pos/len
      const float2 u = buf[idx];
      const float2 v = buf[idx + half];
      const float tr = v.x * t.x - v.y * t.y;
      const float ti = v.x * t.y + v.y * t.x;
      buf[idx]        = make_float2(u.x + tr, u.y + ti);
      buf[idx + half] = make_float2(u.x - tr, u.y - ti);
    }
    __syncthreads();
  }
}

__global__ __launch_bounds__(256) void fft_kernel(
    const float* __restrict__ evolved,   // (4096, 512)
    const float* __restrict__ alpha_p,
    float* __restrict__ ft)              // (4096, 256)
{
  __shared__ float2 buf[4096];           // 32 KB
  __shared__ float2 tw[2048];            // 16 KB twiddles
  const int tid = threadIdx.x;
  const int c = blockIdx.x;
  const float alpha = alpha_p[0];

  for (int k = tid; k < 2048; k += 256) {
    float sn, cs;
    sincosf(-6.283185307179586f * (float)k / 4096.0f, &sn, &cs);
    tw[k] = make_float2(cs, sn);
  }

  for (int t = tid; t < 4096; t += 256) {
    const int r = __brev((unsigned)t) >> 20;
    buf[r] = make_float2(evolved[(size_t)t * HID + 2 * c],
                         evolved[(size_t)t * HID + 2 * c + 1]);
  }
  __syncthreads();
  fft4096(buf, tw, tid);

  for (int t = tid; t < 4096; t += 256) {
    float2 v = buf[t];
    const float km = sqrtf(v.x * v.x + v.y * v.y) + 1e-10f;
    const float pf = alpha * atanf(logf(km));
    float sn, cs;
    sincosf(pf, &sn, &cs);
    const float rr = v.x * cs - v.y * sn;
    const float ii = v.x * sn + v.y * cs;
    buf[t] = make_float2(rr, -ii);
  }
  __syncthreads();
  for (int t = tid; t < 4096; t += 256) {
    const int r = __brev((unsigned)t) >> 20;
    if (r > t) { float2 tmp = buf[t]; buf[t] = buf[r]; buf[r] = tmp; }
  }
  __syncthreads();
  fft4096(buf, tw, tid);

  const float inv = 1.0f / 4096.0f;
  for (int t = tid; t < 4096; t += 256) {
    ft[(size_t)t * NCH + c] = buf[t].x * inv;   // Re(ifft) = Re(fft(conj))/N
  }
}

// ==================== coh = ft @ pc_w.T + pc_b ====================
__global__ __launch_bounds__(256) void coh_kernel(
    const float* __restrict__ ft,     // (4096, 256)
    const float* __restrict__ pcw,    // (128, 256)
    const float* __restrict__ pcb,    // (128)
    float* __restrict__ x0)           // (4096, 128)
{
  __shared__ float wT[64][132];
  __shared__ float fT[64][68];
  const int tid = threadIdx.x;
  const int rg = tid >> 4;
  const int cg = tid & 15;
  const int t0 = blockIdx.x * 64;
  float acc[4][8];
#pragma unroll
  for (int i = 0; i < 4; ++i)
#pragma unroll
    for (int jj = 0; jj < 8; ++jj) acc[i][jj] = 0.f;

  for (int kt = 0; kt < 256; kt += 64) {
    __syncthreads();
    for (int u = tid; u < 64 * DIM; u += 256) {
      const int col = u >> 6, kk = u & 63;
      wT[kk][col] = pcw[col * 256 + kt + kk];
    }
    for (int u = tid; u < 64 * 64; u += 256) {
      const int row = u >> 6, kk = u & 63;
      fT[kk][row] = ft[(size_t)(t0 + row) * NCH + kt + kk];
    }
    __syncthreads();
#pragma unroll 4
    for (int k = 0; k < 64; ++k) {
      const float4 a  = *(const float4*)&fT[k][rg * 4];
      const float4 w0 = *(const float4*)&wT[k][cg * 8];
      const float4 w1 = *(const float4*)&wT[k][cg * 8 + 4];
      const float av[4] = {a.x, a.y, a.z, a.w};
      const float wv[8] = {w0.x, w0.y, w0.z, w0.w, w1.x, w1.y, w1.z, w1.w};
#pragma unroll
      for (int i = 0; i < 4; ++i)
#pragma unroll
        for (int jj = 0; jj < 8; ++jj)
          acc[i][jj] = fmaf(av[i], wv[jj], acc[i][jj]);
    }
  }
#pragma unroll
  for (int i = 0; i < 4; ++i) {
    const int t = t0 + rg * 4 + i;
#pragma unroll
    for (int jj = 0; jj < 8; ++jj)
      x0[(size_t)t * DIM + cg * 8 + jj] = acc[i][jj] + pcb[cg * 8 + jj];
  }
}

// ==================== logits = (x0@Pre.T)^2 + (x0@Pim.T)^2 ====================
__global__ __launch_bounds__(256) void logits_kernel(
    const float* __restrict__ x0,      // (4096, 128)
    const float* __restrict__ patre,   // (32000, 128)
    const float* __restrict__ patim,   // (32000, 128)
    float* __restrict__ out)           // (4096, 32000)
{
  __shared__ float aT[32][68];
  __shared__ float brT[32][132];
  __shared__ float biT[32][132];
  const int tid = threadIdx.x;
  const int tx = tid & 31;
  const int ty = tid >> 5;
  const int m0 = blockIdx.y * 64;
  const int n0 = blockIdx.x * 128;
  float accr[8][4], acci[8][4];
#pragma unroll
  for (int i = 0; i < 8; ++i)
#pragma unroll
    for (int jj = 0; jj < 4; ++jj) { accr[i][jj] = 0.f; acci[i][jj] = 0.f; }

  for (int kt = 0; kt < 128; kt += 32) {
    __syncthreads();
    for (int u = tid; u < 64 * 32; u += 256) {
      const int mm = u >> 5, kk = u & 31;
      aT[kk][mm] = x0[(size_t)(m0 + mm) * DIM + kt + kk];
    }
    for (int u = tid; u < 128 * 32; u += 256) {
      const int nn = u >> 5, kk = u & 31;
      brT[kk][nn] = patre[(size_t)(n0 + nn) * DIM + kt + kk];
      biT[kk][nn] = patim[(size_t)(n0 + nn) * DIM + kt + kk];
    }
    __syncthreads();
#pragma unroll 4
    for (int k = 0; k < 32; ++k) {
      const float4 q0 = *(const float4*)&aT[k][ty * 8];
      const float4 q1 = *(const float4*)&aT[k][ty * 8 + 4];
      const float4 br = *(const float4*)&brT[k][tx * 4];
      const float4 bi = *(const float4*)&biT[k][tx * 4];
      const float av[8]  = {q0.x, q0.y, q0.z, q0.w, q1.x, q1.y, q1.z, q1.w};
      const float brv[4] = {br.x, br.y, br.z, br.w};
      const float biv[4] = {bi.x, bi.y, bi.z, bi.w};
#pragma unroll
      for (int i = 0; i < 8; ++i)
#pragma unroll
        for (int jj = 0; jj < 4; ++jj) {
          accr[i][jj] = fmaf(av[i], brv[jj], accr[i][jj]);
          acci[i][jj] = fmaf(av[i], biv[jj], acci[i][jj]);
        }
    }
  }
#pragma unroll
  for (int i = 0; i < 8; ++i) {
    const size_t m = (size_t)(m0 + ty * 8 + i);
    float4 o;
    o.x = accr[i][0] * accr[i][0] + acci[i][0] * acci[i][0];
    o.y = accr[i][1] * accr[i][1] + acci[i][1] * acci[i][1];
    o.z = accr[i][2] * accr[i][2] + acci[i][2] * acci[i][2];
    o.w = accr[i][3] * accr[i][3] + acci[i][3] * acci[i][3];
    *(float4*)&out[m * VOCAB + n0 + tx * 4] = o;
  }
}

// ============================ launch ============================
extern "C" void kernel_launch(void* const* d_in, const int* in_sizes, int n_in,
                              void* d_out, int out_size, void* d_ws, size_t ws_size,
                              hipStream_t stream)
{
  const float* x     = (const float*)d_in[0];
  const float* w_ih  = (const float*)d_in[1];
  const float* w_hh  = (const float*)d_in[2];
  const float* b_ih  = (const float*)d_in[3];
  const float* b_hh  = (const float*)d_in[4];
  const float* alpha = (const float*)d_in[5];
  const float* pc_w  = (const float*)d_in[6];
  const float* pc_b  = (const float*)d_in[7];
  const float* patre = (const float*)d_in[8];
  const float* patim = (const float*)d_in[9];

  float* out = (float*)d_out;
  // Intermediates parked inside d_out (logits_kernel overwrites all of d_out last)
  float* evolved = out;                 // 4096*512 floats
  float* ft      = out + 4194304;       // 4096*256 floats

  unsigned long long* hg = (unsigned long long*)d_ws;   // 2*512 slots = 8 KB
  float* x0 = (float*)((char*)d_ws + 16384);            // 4096*128 = 2 MB

  // Reset tagged slots every launch (tag 0 == h0 == 0); replay-safe.
  hipMemsetAsync(d_ws, 0, 8192, stream);

  gru_kernel<<<GRU_WGS, 256, 0, stream>>>(x, w_ih, w_hh, b_ih, b_hh, hg, evolved);
  fft_kernel<<<256, 256, 0, stream>>>(evolved, alpha, ft);
  coh_kernel<<<64, 256, 0, stream>>>(ft, pc_w, pc_b, x0);
  logits_kernel<<<dim3(250, 64), 256, 0, stream>>>(x0, patre, patim, out);
}

// Round 12
// 10029.913 us; speedup vs baseline: 1.2501x; 1.0137x over previous
//
#include <hip/hip_runtime.h>

#define T_STEPS 4096
#define HID     512
#define NCH     256
#define DIM     128
#define VOCAB   32000
#define GRU_WGS 32

// ---------- fast transcendentals (hardware v_exp_f32 path; R3-proven) ----------
__device__ __forceinline__ float fast_sigmoid(float x) {
  x = fminf(fmaxf(x, -30.f), 30.f);
  const float e = __expf(-x);
  return __fdividef(1.f, 1.f + e);
}
__device__ __forceinline__ float fast_tanh(float x) {
  x = fminf(fmaxf(x, -15.f), 15.f);
  const float e = __expf(2.f * x);
  return __fdividef(e - 1.f, e + 1.f);
}

// ---------- DPP 16-lane (row) sum; row-lane 0 holds the total (R3-proven) ----------
template <int CTRL>
__device__ __forceinline__ float dpp_add(float v) {
  const int s = __builtin_amdgcn_update_dpp(0, __float_as_int(v), CTRL, 0xF, 0xF, true);
  return v + __int_as_float(s);
}
__device__ __forceinline__ float red16(float v) {
  v = dpp_add<0xB1>(v);   // quad_perm xor1
  v = dpp_add<0x4E>(v);   // quad_perm xor2
  v = dpp_add<0x124>(v);  // row_ror:4
  v = dpp_add<0x128>(v);  // row_ror:8
  return v;               // row-lane 0 (p==0) holds the 16-lane total
}

// ============================ GRU ============================
// Final form = R8 exactly (best measured: 9.19 ms GRU / 10.06 ms total).
// 32 WGs x 256 threads, 16-lane teams per output j. Tagged u64 slots
// (hi32=step tag, lo32=h bits) in d_ws, agent scope. Poll: 2 slots/thread,
// next-round loads issued before the barrier (latency hides under it).
// Publish: plain relaxed agent store (R11 showed RMW-exchange is not faster).
// Per-step floor ~2.25 us = agent-scope publish->detect visibility; verified
// invariant to poll width (R9), mailbox topology (R10), publish op (R11).
__global__ __launch_bounds__(256) void gru_kernel(
    const float* __restrict__ x,
    const float* __restrict__ w_ih,
    const float* __restrict__ w_hh,
    const float* __restrict__ b_ih,
    const float* __restrict__ b_hh,
    unsigned long long* hg,            // 2 * 512 tagged slots (zeroed each launch)
    float* __restrict__ evolved)       // (4096, 512)
{
  __shared__ float hs[HID];            // 2 KB
  __shared__ float xl[T_STEPS];        // 16 KB: x staged once
  const int tid  = threadIdx.x;
  const int wave = tid >> 6;
  const int lane = tid & 63;
  const int team = lane >> 4;          // 0..3
  const int p    = lane & 15;          // k-slice index within team
  const int pr   = p & 7;              // bank-rotation amount
  const int j    = blockIdx.x * 16 + wave * 4 + team;   // 0..511
  const int k0   = p * 32;

  // stage x into LDS (coalesced float4), consumed after first barrier
  {
    const float4* x4 = reinterpret_cast<const float4*>(x);
    float4* xl4 = reinterpret_cast<float4*>(xl);
    for (int u = tid; u < T_STEPS / 4; u += 256) xl4[u] = x4[u];
  }

  // weights rows j (r), 512+j (z), 1024+j (n), cols [32p,32p+32), rotated order
  float4 w[3][8];
#pragma unroll
  for (int d = 0; d < 3; ++d) {
    const float4* wr = reinterpret_cast<const float4*>(w_hh + (size_t)(d * HID + j) * HID);
#pragma unroll
    for (int qq = 0; qq < 8; ++qq) {
      const int r = (qq + pr) & 7;
      w[d][qq] = wr[p * 8 + r];
    }
  }
  float c3[3], bi3[3], bh3[3];
#pragma unroll
  for (int d = 0; d < 3; ++d) {
    int r = d * HID + j;
    c3[d]  = w_ih[r*4+0] + 0.1f*w_ih[r*4+1] + 0.01f*w_ih[r*4+2] + 0.001f*w_ih[r*4+3];
    bi3[d] = b_ih[r];
    bh3[d] = b_hh[r];
  }
  __syncthreads();   // xl[] visible to all before first use

  float hprev = 0.0f;  // leader lanes (p==0) carry h[j]
  for (int s = 1; s <= T_STEPS; ++s) {
    const int rb = (s - 1) & 1;
    const int wb = s & 1;
    const unsigned int want = (unsigned int)(s - 1);
    const unsigned long long* rs = hg + rb * HID;

    const float xt = xl[s - 1];

    // ---- WG-cooperative poll with next-round prefetch (R8-proven) ----
    unsigned long long vA, vB;
    vA = __hip_atomic_load(rs + 2 * tid,     __ATOMIC_RELAXED, __HIP_MEMORY_SCOPE_AGENT);
    vB = __hip_atomic_load(rs + 2 * tid + 1, __ATOMIC_RELAXED, __HIP_MEMORY_SCOPE_AGENT);
    for (;;) {
      const bool ok = ((unsigned int)(vA >> 32) == want) &
                      ((unsigned int)(vB >> 32) == want);
      // issue next round's loads BEFORE the barrier: latency hides under it
      const unsigned long long nA =
          __hip_atomic_load(rs + 2 * tid,     __ATOMIC_RELAXED, __HIP_MEMORY_SCOPE_AGENT);
      const unsigned long long nB =
          __hip_atomic_load(rs + 2 * tid + 1, __ATOMIC_RELAXED, __HIP_MEMORY_SCOPE_AGENT);
      if (__syncthreads_and(ok)) break;
      vA = nA; vB = nB;
    }
    hs[2 * tid]     = __uint_as_float((unsigned int)vA);
    hs[2 * tid + 1] = __uint_as_float((unsigned int)vB);
    __syncthreads();

    // ---- dot products from LDS (rotated order; sum is order-invariant) ----
    float a0 = 0.f, a1 = 0.f, a2 = 0.f;
#pragma unroll
    for (int qq = 0; qq < 8; ++qq) {
      const int r = (qq + pr) & 7;
      const float4 h4 = *reinterpret_cast<const float4*>(&hs[k0 + 4 * r]);
      a0 = fmaf(w[0][qq].x, h4.x, a0);
      a0 = fmaf(w[0][qq].y, h4.y, a0);
      a0 = fmaf(w[0][qq].z, h4.z, a0);
      a0 = fmaf(w[0][qq].w, h4.w, a0);
      a1 = fmaf(w[1][qq].x, h4.x, a1);
      a1 = fmaf(w[1][qq].y, h4.y, a1);
      a1 = fmaf(w[1][qq].z, h4.z, a1);
      a1 = fmaf(w[1][qq].w, h4.w, a1);
      a2 = fmaf(w[2][qq].x, h4.x, a2);
      a2 = fmaf(w[2][qq].y, h4.y, a2);
      a2 = fmaf(w[2][qq].z, h4.z, a2);
      a2 = fmaf(w[2][qq].w, h4.w, a2);
    }

    // ---- DPP team reduce (VALU-only; leaders are row-lane 0) ----
    a0 = red16(a0); a1 = red16(a1); a2 = red16(a2);

    if (p == 0) {
      const float rg = fast_sigmoid(fmaf(xt, c3[0], bi3[0]) + a0 + bh3[0]);
      const float zg = fast_sigmoid(fmaf(xt, c3[1], bi3[1]) + a1 + bh3[1]);
      const float ng = fast_tanh(fmaf(xt, c3[2], bi3[2]) + rg * (a2 + bh3[2]));
      const float hn = (1.0f - zg) * ng + zg * hprev;
      hprev = hn;
      const unsigned long long pk =
          ((unsigned long long)(unsigned int)s << 32) | (unsigned long long)__float_as_uint(hn);
      __hip_atomic_store(hg + wb * HID + j, pk, __ATOMIC_RELAXED, __HIP_MEMORY_SCOPE_AGENT);
      evolved[(size_t)(s - 1) * HID + j] = hn;
    }
  }
}

// ==================== FFT -> phase filter -> IFFT ====================
// 4096-pt radix-2 DIT with a 2048-entry LDS twiddle table (R8-proven).
__device__ __forceinline__ void fft4096(float2* buf, const float2* tw, int tid)
{
  for (int st = 0; st < 12; ++st) {
    const int half = 1 << st;
    const int sh = 11 - st;
    for (int i = tid; i < 2048; i += 256) {
      const int blk = i >> st;
      const int pos = i & (half - 1);
      const int idx = blk * (2 << st) + pos;
      const float2 t = tw[pos << sh];       // (cos, sin) of -2*pi*pos/len
      const float2 u = buf[idx];
      const float2 v = buf[idx + half];
      const float tr = v.x * t.x - v.y * t.y;
      const float ti = v.x * t.y + v.y * t.x;
      buf[idx]        = make_float2(u.x + tr, u.y + ti);
      buf[idx + half] = make_float2(u.x - tr, u.y - ti);
    }
    __syncthreads();
  }
}

__global__ __launch_bounds__(256) void fft_kernel(
    const float* __restrict__ evolved,   // (4096, 512)
    const float* __restrict__ alpha_p,
    float* __restrict__ ft)              // (4096, 256)
{
  __shared__ float2 buf[4096];           // 32 KB
  __shared__ float2 tw[2048];            // 16 KB twiddles
  const int tid = threadIdx.x;
  const int c = blockIdx.x;
  const float alpha = alpha_p[0];

  for (int k = tid; k < 2048; k += 256) {
    float sn, cs;
    sincosf(-6.283185307179586f * (float)k / 4096.0f, &sn, &cs);
    tw[k] = make_float2(cs, sn);
  }

  for (int t = tid; t < 4096; t += 256) {
    const int r = __brev((unsigned)t) >> 20;
    buf[r] = make_float2(evolved[(size_t)t * HID + 2 * c],
                         evolved[(size_t)t * HID + 2 * c + 1]);
  }
  __syncthreads();
  fft4096(buf, tw, tid);

  for (int t = tid; t < 4096; t += 256) {
    float2 v = buf[t];
    const float km = sqrtf(v.x * v.x + v.y * v.y) + 1e-10f;
    const float pf = alpha * atanf(logf(km));
    float sn, cs;
    sincosf(pf, &sn, &cs);
    const float rr = v.x * cs - v.y * sn;
    const float ii = v.x * sn + v.y * cs;
    buf[t] = make_float2(rr, -ii);
  }
  __syncthreads();
  for (int t = tid; t < 4096; t += 256) {
    const int r = __brev((unsigned)t) >> 20;
    if (r > t) { float2 tmp = buf[t]; buf[t] = buf[r]; buf[r] = tmp; }
  }
  __syncthreads();
  fft4096(buf, tw, tid);

  const float inv = 1.0f / 4096.0f;
  for (int t = tid; t < 4096; t += 256) {
    ft[(size_t)t * NCH + c] = buf[t].x * inv;   // Re(ifft) = Re(fft(conj))/N
  }
}

// ==================== coh = ft @ pc_w.T + pc_b ====================
__global__ __launch_bounds__(256) void coh_kernel(
    const float* __restrict__ ft,     // (4096, 256)
    const float* __restrict__ pcw,    // (128, 256)
    const float* __restrict__ pcb,    // (128)
    float* __restrict__ x0)           // (4096, 128)
{
  __shared__ float wT[64][132];
  __shared__ float fT[64][68];
  const int tid = threadIdx.x;
  const int rg = tid >> 4;
  const int cg = tid & 15;
  const int t0 = blockIdx.x * 64;
  float acc[4][8];
#pragma unroll
  for (int i = 0; i < 4; ++i)
#pragma unroll
    for (int jj = 0; jj < 8; ++jj) acc[i][jj] = 0.f;

  for (int kt = 0; kt < 256; kt += 64) {
    __syncthreads();
    for (int u = tid; u < 64 * DIM; u += 256) {
      const int col = u >> 6, kk = u & 63;
      wT[kk][col] = pcw[col * 256 + kt + kk];
    }
    for (int u = tid; u < 64 * 64; u += 256) {
      const int row = u >> 6, kk = u & 63;
      fT[kk][row] = ft[(size_t)(t0 + row) * NCH + kt + kk];
    }
    __syncthreads();
#pragma unroll 4
    for (int k = 0; k < 64; ++k) {
      const float4 a  = *(const float4*)&fT[k][rg * 4];
      const float4 w0 = *(const float4*)&wT[k][cg * 8];
      const float4 w1 = *(const float4*)&wT[k][cg * 8 + 4];
      const float av[4] = {a.x, a.y, a.z, a.w};
      const float wv[8] = {w0.x, w0.y, w0.z, w0.w, w1.x, w1.y, w1.z, w1.w};
#pragma unroll
      for (int i = 0; i < 4; ++i)
#pragma unroll
        for (int jj = 0; jj < 8; ++jj)
          acc[i][jj] = fmaf(av[i], wv[jj], acc[i][jj]);
    }
  }
#pragma unroll
  for (int i = 0; i < 4; ++i) {
    const int t = t0 + rg * 4 + i;
#pragma unroll
    for (int jj = 0; jj < 8; ++jj)
      x0[(size_t)t * DIM + cg * 8 + jj] = acc[i][jj] + pcb[cg * 8 + jj];
  }
}

// ==================== logits = (x0@Pre.T)^2 + (x0@Pim.T)^2 ====================
__global__ __launch_bounds__(256) void logits_kernel(
    const float* __restrict__ x0,      // (4096, 128)
    const float* __restrict__ patre,   // (32000, 128)
    const float* __restrict__ patim,   // (32000, 128)
    float* __restrict__ out)           // (4096, 32000)
{
  __shared__ float aT[32][68];
  __shared__ float brT[32][132];
  __shared__ float biT[32][132];
  const int tid = threadIdx.x;
  const int tx = tid & 31;
  const int ty = tid >> 5;
  const int m0 = blockIdx.y * 64;
  const int n0 = blockIdx.x * 128;
  float accr[8][4], acci[8][4];
#pragma unroll
  for (int i = 0; i < 8; ++i)
#pragma unroll
    for (int jj = 0; jj < 4; ++jj) { accr[i][jj] = 0.f; acci[i][jj] = 0.f; }

  for (int kt = 0; kt < 128; kt += 32) {
    __syncthreads();
    for (int u = tid; u < 64 * 32; u += 256) {
      const int mm = u >> 5, kk = u & 31;
      aT[kk][mm] = x0[(size_t)(m0 + mm) * DIM + kt + kk];
    }
    for (int u = tid; u < 128 * 32; u += 256) {
      const int nn = u >> 5, kk = u & 31;
      brT[kk][nn] = patre[(size_t)(n0 + nn) * DIM + kt + kk];
      biT[kk][nn] = patim[(size_t)(n0 + nn) * DIM + kt + kk];
    }
    __syncthreads();
#pragma unroll 4
    for (int k = 0; k < 32; ++k) {
      const float4 q0 = *(const float4*)&aT[k][ty * 8];
      const float4 q1 = *(const float4*)&aT[k][ty * 8 + 4];
      const float4 br = *(const float4*)&brT[k][tx * 4];
      const float4 bi = *(const float4*)&biT[k][tx * 4];
      const float av[8]  = {q0.x, q0.y, q0.z, q0.w, q1.x, q1.y, q1.z, q1.w};
      const float brv[4] = {br.x, br.y, br.z, br.w};
      const float biv[4] = {bi.x, bi.y, bi.z, bi.w};
#pragma unroll
      for (int i = 0; i < 8; ++i)
#pragma unroll
        for (int jj = 0; jj < 4; ++jj) {
          accr[i][jj] = fmaf(av[i], brv[jj], accr[i][jj]);
          acci[i][jj] = fmaf(av[i], biv[jj], acci[i][jj]);
        }
    }
  }
#pragma unroll
  for (int i = 0; i < 8; ++i) {
    const size_t m = (size_t)(m0 + ty * 8 + i);
    float4 o;
    o.x = accr[i][0] * accr[i][0] + acci[i][0] * acci[i][0];
    o.y = accr[i][1] * accr[i][1] + acci[i][1] * acci[i][1];
    o.z = accr[i][2] * accr[i][2] + acci[i][2] * acci[i][2];
    o.w = accr[i][3] * accr[i][3] + acci[i][3] * acci[i][3];
    *(float4*)&out[m * VOCAB + n0 + tx * 4] = o;
  }
}

// ============================ launch ============================
extern "C" void kernel_launch(void* const* d_in, const int* in_sizes, int n_in,
                              void* d_out, int out_size, void* d_ws, size_t ws_size,
                              hipStream_t stream)
{
  const float* x     = (const float*)d_in[0];
  const float* w_ih  = (const float*)d_in[1];
  const float* w_hh  = (const float*)d_in[2];
  const float* b_ih  = (const float*)d_in[3];
  const float* b_hh  = (const float*)d_in[4];
  const float* alpha = (const float*)d_in[5];
  const float* pc_w  = (const float*)d_in[6];
  const float* pc_b  = (const float*)d_in[7];
  const float* patre = (const float*)d_in[8];
  const float* patim = (const float*)d_in[9];

  float* out = (float*)d_out;
  // Intermediates parked inside d_out (logits_kernel overwrites all of d_out last)
  float* evolved = out;                 // 4096*512 floats
  float* ft      = out + 4194304;       // 4096*256 floats

  unsigned long long* hg = (unsigned long long*)d_ws;   // 2*512 slots = 8 KB
  float* x0 = (float*)((char*)d_ws + 16384);            // 4096*128 = 2 MB

  // Reset tagged slots every launch (tag 0 == h0 == 0); replay-safe.
  hipMemsetAsync(d_ws, 0, 8192, stream);

  gru_kernel<<<GRU_WGS, 256, 0, stream>>>(x, w_ih, w_hh, b_ih, b_hh, hg, evolved);
  fft_kernel<<<256, 256, 0, stream>>>(evolved, alpha, ft);
  coh_kernel<<<64, 256, 0, stream>>>(ft, pc_w, pc_b, x0);
  logits_kernel<<<dim3(250, 64), 256, 0, stream>>>(x0, patre, patim, out);
}